// Round 10
// baseline (21730.992 us; speedup 1.0000x reference)
//
#include <hip/hip_runtime.h>

#define T_SEQ 8192
#define HDIM  2048
#define EDIM  2048
#define RBLK  64                      // recurrence blocks; 32 rows each

typedef unsigned long long u64;
typedef __attribute__((ext_vector_type(4))) unsigned int u32x4;
typedef __attribute__((ext_vector_type(4))) float f32x4;

// two 16B agent-coherent loads + full drain (proven poll)
__device__ inline void poll_pair(const u64* p0, const u64* p1, u32x4& a, u32x4& b) {
    asm volatile("global_load_dwordx4 %0, %2, off sc1\n\t"
                 "global_load_dwordx4 %1, %3, off sc1\n\t"
                 "s_waitcnt vmcnt(0)"
                 : "=v"(a), "=v"(b) : "v"(p0), "v"(p1) : "memory");
}

// Non-rematerializable 16B load: result MUST live in registers (asm output).
__device__ inline f32x4 ld_w16(const float* p) {
    f32x4 r;
    asm volatile("global_load_dwordx4 %0, %1, off" : "=v"(r) : "v"(p));
    return r;
}

// tanh via e^{2z}: clamp +-15, exp2, rcp. ~6 VALU ops (validated R8/R9).
__device__ inline float fast_tanh(float z) {
    float zc = fminf(fmaxf(z, -15.f), 15.f);
    float zs = zc * 2.88539008177792681f;   // 2*log2(e)
    float ez; asm("v_exp_f32 %0, %1" : "=v"(ez) : "v"(zs));
    float rc; float ezp = ez + 1.f;
    asm("v_rcp_f32 %0, %1" : "=v"(rc) : "v"(ezp));
    return (ez - 1.f) * rc;
}

// ---------------------------------------------------------------------------
// GEMM (NT): C[m][n] = sum_k A[m][k] * B[n][k] + bias[n]
// ---------------------------------------------------------------------------
__global__ __launch_bounds__(256) void gemm_nt_bias(
    const float* __restrict__ A, const float* __restrict__ B,
    const float* __restrict__ bias, float* __restrict__ C,
    int M, int N, int K)
{
    constexpr int BK = 32;
    __shared__ float As[BK][64 + 4];
    __shared__ float Bs[BK][64 + 4];

    const int tx = threadIdx.x & 15;
    const int ty = threadIdx.x >> 4;
    const int m0 = blockIdx.y * 64;
    const int n0 = blockIdx.x * 64;

    float acc[4][4] = {};

    for (int kk = 0; kk < K; kk += BK) {
        #pragma unroll
        for (int p = 0; p < 8; ++p) {
            int idx = p * 256 + threadIdx.x;
            int r = idx >> 5;
            int c = idx & 31;
            As[c][r] = A[(size_t)(m0 + r) * K + kk + c];
            Bs[c][r] = B[(size_t)(n0 + r) * K + kk + c];
        }
        __syncthreads();
        #pragma unroll
        for (int k = 0; k < BK; ++k) {
            float4 a = *(const float4*)&As[k][ty * 4];
            float4 b = *(const float4*)&Bs[k][tx * 4];
            float av[4] = {a.x, a.y, a.z, a.w};
            float bv[4] = {b.x, b.y, b.z, b.w};
            #pragma unroll
            for (int i = 0; i < 4; ++i)
                #pragma unroll
                for (int j = 0; j < 4; ++j)
                    acc[i][j] = fmaf(av[i], bv[j], acc[i][j]);
        }
        __syncthreads();
    }

    float4 bb = *(const float4*)&bias[n0 + tx * 4];
    float bvv[4] = {bb.x, bb.y, bb.z, bb.w};
    #pragma unroll
    for (int i = 0; i < 4; ++i) {
        float4 o;
        o.x = acc[i][0] + bvv[0];
        o.y = acc[i][1] + bvv[1];
        o.z = acc[i][2] + bvv[2];
        o.w = acc[i][3] + bvv[3];
        *(float4*)&C[(size_t)(m0 + ty * 4 + i) * N + n0 + tx * 4] = o;
    }
}

// ---------------------------------------------------------------------------
// Same GEMM, TRANSPOSED output: Ct[n][m] (for xpT row-major-in-t locality).
// ---------------------------------------------------------------------------
__global__ __launch_bounds__(256) void gemm_nt_bias_tc(
    const float* __restrict__ A, const float* __restrict__ B,
    const float* __restrict__ bias, float* __restrict__ Ct,
    int M, int N, int K)
{
    constexpr int BK = 32;
    __shared__ float As[BK][64 + 4];
    __shared__ float Bs[BK][64 + 4];

    const int tx = threadIdx.x & 15;
    const int ty = threadIdx.x >> 4;
    const int m0 = blockIdx.y * 64;
    const int n0 = blockIdx.x * 64;

    float acc[4][4] = {};

    for (int kk = 0; kk < K; kk += BK) {
        #pragma unroll
        for (int p = 0; p < 8; ++p) {
            int idx = p * 256 + threadIdx.x;
            int r = idx >> 5;
            int c = idx & 31;
            As[c][r] = A[(size_t)(m0 + r) * K + kk + c];
            Bs[c][r] = B[(size_t)(n0 + r) * K + kk + c];
        }
        __syncthreads();
        #pragma unroll
        for (int k = 0; k < BK; ++k) {
            float4 a = *(const float4*)&As[k][ty * 4];
            float4 b = *(const float4*)&Bs[k][tx * 4];
            float av[4] = {a.x, a.y, a.z, a.w};
            float bv[4] = {b.x, b.y, b.z, b.w};
            #pragma unroll
            for (int i = 0; i < 4; ++i)
                #pragma unroll
                for (int j = 0; j < 4; ++j)
                    acc[i][j] = fmaf(av[i], bv[j], acc[i][j]);
        }
        __syncthreads();
    }

    float4 bb = *(const float4*)&bias[n0 + tx * 4];
    float bvv[4] = {bb.x, bb.y, bb.z, bb.w};
    #pragma unroll
    for (int j = 0; j < 4; ++j) {
        float4 o;
        o.x = acc[0][j] + bvv[j];
        o.y = acc[1][j] + bvv[j];
        o.z = acc[2][j] + bvv[j];
        o.w = acc[3][j] + bvv[j];
        *(float4*)&Ct[(size_t)(n0 + tx * 4 + j) * M + m0 + ty * 4] = o;
    }
}

// ---------------------------------------------------------------------------
// Recurrence, COLUMN-SLICED decomposition (R10):
//   Block b owns output rows r0=b*32..+31. Thread tid polls h columns
//   c0=tid*4..+3 (32B contiguous) and holds W[r0+r][c0..c0+3] for ALL 32
//   rows in 128 VGPRs. Dot runs register-only (h from poll regs, W from
//   regs): 128 FMAs -> 32 partials -> 6-level butterfly fold (32 shfl for
//   all 32 rows) -> 32 floats/wave to LDS -> barrier -> wave 0 sums 8
//   partials/row + xq + tanh + tagged store. h NEVER staged in LDS (R9's
//   500-770cy/step LDS-BW term eliminated); a thread's FMAs start as soon
//   as ITS 4 words arrive (overlaps writer-arrival spread).
// Sync: hbuf[2][HDIM] u64 (tag<<32|f32bits), tag travels with data, plain
// relaxed agent-scope stores. Overwrite safety: wave0's tag-(t+1) store
// value-depends (partials + barrier) on ALL threads' tag-t polls.
// ---------------------------------------------------------------------------
__global__ __launch_bounds__(512, 1) void rnn_recurrence(
    const float* __restrict__ Wh, const float* __restrict__ xpT,
    float* __restrict__ Hs, u64* __restrict__ hbuf, int T)
{
    const int tid  = threadIdx.x;
    const int lane = tid & 63;
    const int wid  = tid >> 6;               // 0..7
    const int r0   = blockIdx.x * 32;        // block's 32 output rows
    const int c0   = tid * 4;                // this thread's 4 h columns

    // w[r] = Wh[r0+r][c0..c0+3]  (128 VGPRs, asm-loaded = non-remat)
    f32x4 w[32];
    #pragma unroll
    for (int r = 0; r < 32; ++r)
        w[r] = ld_w16(Wh + (size_t)(r0 + r) * HDIM + c0);
    asm volatile("s_waitcnt vmcnt(0)" ::: "memory");

    __shared__ float pw[8 * 32];   // per-wave row partials

    for (int t = 0; t < T; ++t) {
        if (t > 0) {
            const u64* hb = hbuf + (size_t)(t & 1) * HDIM + c0;
            const unsigned tg = (unsigned)t;

            u32x4 a, b;
            poll_pair(hb, hb + 2, a, b);
            while ((a.y != tg) | (a.w != tg) | (b.y != tg) | (b.w != tg))
                poll_pair(hb, hb + 2, a, b);

            const float h0 = __uint_as_float(a.x), h1 = __uint_as_float(a.z);
            const float h2 = __uint_as_float(b.x), h3 = __uint_as_float(b.z);

            // 32 per-row partials, register-only
            float s[32];
            #pragma unroll
            for (int r = 0; r < 32; ++r) {
                float acc =      w[r].x * h0;
                acc = fmaf(w[r].y, h1, acc);
                acc = fmaf(w[r].z, h2, acc);
                acc = fmaf(w[r].w, h3, acc);
                s[r] = acc;
            }

            // butterfly fold: after 5 steps lane holds row (lane&31) summed
            // over its 32-lane half; one xor-32 completes the 64-lane sum.
            #pragma unroll
            for (int step = 0; step < 5; ++step) {
                const int off = 1 << step;
                const bool up = (lane & off) != 0;
                #pragma unroll
                for (int j = 0; j < (32 >> (step + 1)); ++j) {
                    float aa = s[2 * j], bb = s[2 * j + 1];
                    float lo = up ? bb : aa;
                    float hi = up ? aa : bb;
                    s[j] = lo + __shfl_xor(hi, off);
                }
            }
            float rowsum = s[0] + __shfl_xor(s[0], 32);
            if (lane < 32) pw[wid * 32 + lane] = rowsum;
        }
        __syncthreads();

        if (wid == 0) {
            const int l = lane & 31;
            float sum = 0.f;
            if (t > 0) {
                #pragma unroll
                for (int k = 0; k < 8; ++k) sum += pw[k * 32 + l];
            }
            float xq = xpT[(size_t)(r0 + l) * T + t];   // L1-hot 15/16 steps
            float hn = fast_tanh(sum + xq);
            if (lane < 32) {
                u64 pk = ((u64)(unsigned)(t + 1) << 32) | (u64)__float_as_uint(hn);
                __hip_atomic_store(&hbuf[(size_t)((t + 1) & 1) * HDIM + r0 + lane],
                                   pk, __ATOMIC_RELAXED, __HIP_MEMORY_SCOPE_AGENT);
                Hs[(size_t)t * HDIM + r0 + lane] = hn;
            }
        }
        // no trailing barrier: other waves' next pw writes are gated by their
        // poll success, which requires wave0's value-dependent tagged stores.
    }
}

// ---------------------------------------------------------------------------
// Row softmax over EDIM=2048: one block (256 threads) per row.
// ---------------------------------------------------------------------------
__global__ __launch_bounds__(256) void softmax_rows(
    const float* __restrict__ logits, float* __restrict__ out)
{
    const int row = blockIdx.x;
    const float4* in4 = (const float4*)(logits + (size_t)row * EDIM);
    float4* out4 = (float4*)(out + (size_t)row * EDIM);

    float4 v0 = in4[threadIdx.x];
    float4 v1 = in4[threadIdx.x + 256];

    float m = fmaxf(fmaxf(fmaxf(v0.x, v0.y), fmaxf(v0.z, v0.w)),
                    fmaxf(fmaxf(v1.x, v1.y), fmaxf(v1.z, v1.w)));
    #pragma unroll
    for (int off = 32; off > 0; off >>= 1) m = fmaxf(m, __shfl_xor(m, off));

    __shared__ float red[4];
    if ((threadIdx.x & 63) == 0) red[threadIdx.x >> 6] = m;
    __syncthreads();
    m = fmaxf(fmaxf(red[0], red[1]), fmaxf(red[2], red[3]));
    __syncthreads();

    float e[8];
    e[0] = expf(v0.x - m); e[1] = expf(v0.y - m);
    e[2] = expf(v0.z - m); e[3] = expf(v0.w - m);
    e[4] = expf(v1.x - m); e[5] = expf(v1.y - m);
    e[6] = expf(v1.z - m); e[7] = expf(v1.w - m);

    float s = e[0] + e[1] + e[2] + e[3] + e[4] + e[5] + e[6] + e[7];
    #pragma unroll
    for (int off = 32; off > 0; off >>= 1) s += __shfl_xor(s, off);
    if ((threadIdx.x & 63) == 0) red[threadIdx.x >> 6] = s;
    __syncthreads();
    s = red[0] + red[1] + red[2] + red[3];

    float inv = 1.0f / s;
    out4[threadIdx.x]       = make_float4(e[0] * inv, e[1] * inv, e[2] * inv, e[3] * inv);
    out4[threadIdx.x + 256] = make_float4(e[4] * inv, e[5] * inv, e[6] * inv, e[7] * inv);
}

__global__ void copy_vec(const float* __restrict__ src, float* __restrict__ dst, int n)
{
    int i = blockIdx.x * blockDim.x + threadIdx.x;
    if (i < n) dst[i] = src[i];
}

// ---------------------------------------------------------------------------
extern "C" void kernel_launch(void* const* d_in, const int* in_sizes, int n_in,
                              void* d_out, int out_size, void* d_ws, size_t ws_size,
                              hipStream_t stream)
{
    const float* x  = (const float*)d_in[0];   // [T_SEQ][EDIM]
    const float* Wh = (const float*)d_in[1];   // [HDIM][HDIM]
    const float* Wx = (const float*)d_in[2];   // [HDIM][EDIM]
    const float* Wy = (const float*)d_in[3];   // [EDIM][HDIM]
    const float* Bh = (const float*)d_in[4];   // [HDIM]
    const float* By = (const float*)d_in[5];   // [EDIM]

    float* out    = (float*)d_out;
    float* hfinal = out;                 // [HDIM]
    float* hs     = out + HDIM;          // [T_SEQ][HDIM]: holds hs, then probs

    float* xpT  = (float*)d_ws;                                   // [HDIM][T_SEQ]
    u64*   hbuf = (u64*)((char*)d_ws + (size_t)T_SEQ * HDIM * 4); // [2][HDIM]
    float* logits = xpT;                 // reuse (xpT dead after recurrence)

    // clear tagged h buffers so replays never see stale tags
    hipMemsetAsync(hbuf, 0, 2 * HDIM * sizeof(u64), stream);

    // Phase 1: xpT = (x @ Wx^T + Bh)^T   -> [HDIM][T_SEQ]
    gemm_nt_bias_tc<<<dim3(HDIM / 64, T_SEQ / 64), 256, 0, stream>>>(
        x, Wx, Bh, xpT, T_SEQ, HDIM, EDIM);

    // Phase 2: recurrence — cooperative launch only to guarantee co-residency
    int T = T_SEQ;
    const float* xpT_c = xpT;
    void* args[] = {(void*)&Wh, (void*)&xpT_c, (void*)&hs, (void*)&hbuf, (void*)&T};
    hipLaunchCooperativeKernel((void*)rnn_recurrence, dim3(RBLK), dim3(512),
                               args, 0, stream);

    // Phase 3: logits = hs @ Wy^T + By   (normal [T][E] layout)
    gemm_nt_bias<<<dim3(EDIM / 64, T_SEQ / 64), 256, 0, stream>>>(
        hs, Wy, By, logits, T_SEQ, EDIM, HDIM);

    // Phase 4: h_final = hs[T-1] (before softmax overwrites hs region)
    copy_vec<<<dim3(HDIM / 256), 256, 0, stream>>>(
        hs + (size_t)(T_SEQ - 1) * HDIM, hfinal, HDIM);

    // Phase 5: softmax rows: logits (ws) -> output region of d_out
    softmax_rows<<<dim3(T_SEQ), 256, 0, stream>>>(logits, hs);
}